// Round 3
// baseline (91.433 us; speedup 1.0000x reference)
//
#include <hip/hip_runtime.h>

typedef unsigned int uint;

#define BATCH 8
#define HH 128
#define WW 128
#define CC 64
#define NPIX (BATCH * HH * WW)   // 131072
#define KK 9
#define BN_EPS 1e-3f

// ---- setup: transpose w1, fold b1 + BN into per-channel scale/bias ----
__global__ void setup_kernel(const float* __restrict__ w1,
                             const float* __restrict__ b1,
                             const float* __restrict__ gamma,
                             const float* __restrict__ beta,
                             const float* __restrict__ bn_mean,
                             const float* __restrict__ bn_var,
                             const float* __restrict__ w2,
                             const float* __restrict__ b2,
                             float* __restrict__ w1t,    // [64][64]: w1t[d][c] = w1[c][d]
                             float* __restrict__ w2f,    // [64][9]
                             float* __restrict__ scalef, // [64]
                             float* __restrict__ biasf,  // [64]
                             float* __restrict__ b2f)    // [9]
{
    int t = blockIdx.x * blockDim.x + threadIdx.x;
    int nt = gridDim.x * blockDim.x;
    for (int idx = t; idx < CC * CC; idx += nt) {
        int d = idx >> 6, c = idx & 63;
        w1t[idx] = w1[c * CC + d];
    }
    for (int idx = t; idx < CC * KK; idx += nt) w2f[idx] = w2[idx];
    if (t < CC) {
        float s = gamma[t] * rsqrtf(bn_var[t] + BN_EPS);
        scalef[t] = s;
        biasf[t] = (b1[t] - bn_mean[t]) * s + beta[t];
    }
    if (t < KK) b2f[t] = b2[t];
}

// ---- main fused kernel: 1 thread = 1 pixel ----
__global__ __launch_bounds__(256) void invol_kernel(
    const float* __restrict__ x,
    const float* __restrict__ w1t,
    const float* __restrict__ w2f,
    const float* __restrict__ scalef,
    const float* __restrict__ biasf,
    const float* __restrict__ b2f,
    float* __restrict__ out,     // [NPIX][64]
    float* __restrict__ kout)    // [NPIX][9]
{
    int p = blockIdx.x * blockDim.x + threadIdx.x;
    if (p >= NPIX) return;
    int b = p >> 14;          // /(HH*WW)
    int ij = p & 16383;
    int i = ij >> 7;
    int j = ij & 127;

    // ---- load x[p][0..63] into f32 regs ----
    float xr[CC];
    const float4* xp = (const float4*)(x + (size_t)p * CC);
#pragma unroll
    for (int q = 0; q < 16; ++q) {
        float4 v = xp[q];
        xr[4 * q + 0] = v.x; xr[4 * q + 1] = v.y;
        xr[4 * q + 2] = v.z; xr[4 * q + 3] = v.w;
    }

    // ---- step 1+2: h = relu(bn(x@w1)), kern = h@w2 + b2, fused over d ----
    float kern[KK];
#pragma unroll
    for (int k = 0; k < KK; ++k) kern[k] = b2f[k];

#pragma unroll 1
    for (int d0 = 0; d0 < CC; d0 += 4) {
        float h0 = 0.f, h1 = 0.f, h2 = 0.f, h3 = 0.f;
        const float* w0 = w1t + d0 * CC;
#pragma unroll
        for (int c = 0; c < CC; ++c) {
            float xv = xr[c];
            h0 = fmaf(xv, w0[c], h0);
            h1 = fmaf(xv, w0[c + CC], h1);
            h2 = fmaf(xv, w0[c + 2 * CC], h2);
            h3 = fmaf(xv, w0[c + 3 * CC], h3);
        }
        h0 = fmaxf(fmaf(h0, scalef[d0 + 0], biasf[d0 + 0]), 0.f);
        h1 = fmaxf(fmaf(h1, scalef[d0 + 1], biasf[d0 + 1]), 0.f);
        h2 = fmaxf(fmaf(h2, scalef[d0 + 2], biasf[d0 + 2]), 0.f);
        h3 = fmaxf(fmaf(h3, scalef[d0 + 3], biasf[d0 + 3]), 0.f);
#pragma unroll
        for (int k = 0; k < KK; ++k) {
            float acc = kern[k];
            acc = fmaf(h0, w2f[(d0 + 0) * KK + k], acc);
            acc = fmaf(h1, w2f[(d0 + 1) * KK + k], acc);
            acc = fmaf(h2, w2f[(d0 + 2) * KK + k], acc);
            acc = fmaf(h3, w2f[(d0 + 3) * KK + k], acc);
            kern[k] = acc;
        }
    }

    // ---- write kern (output 2, f32) ----
#pragma unroll
    for (int k = 0; k < KK; ++k) kout[(size_t)p * KK + k] = kern[k];

    // ---- involution: out[c] = sum_k kern[k] * x[nbr_k][c] ----
    float acc[CC];
    float kc = kern[4];   // center tap reuses regs
#pragma unroll
    for (int c = 0; c < CC; ++c) acc[c] = kc * xr[c];

#pragma unroll
    for (int t = 0; t < KK; ++t) {
        if (t == 4) continue;
        int di = t / 3 - 1, dj = t % 3 - 1;
        int ii = i + di, jj = j + dj;
        if (ii < 0 || ii > HH - 1 || jj < 0 || jj > WW - 1) continue;
        const float4* np = (const float4*)(x + (((size_t)b * HH + ii) * WW + jj) * CC);
        float kv = kern[t];
#pragma unroll
        for (int q = 0; q < 16; ++q) {
            float4 v = np[q];
            acc[4 * q + 0] = fmaf(kv, v.x, acc[4 * q + 0]);
            acc[4 * q + 1] = fmaf(kv, v.y, acc[4 * q + 1]);
            acc[4 * q + 2] = fmaf(kv, v.z, acc[4 * q + 2]);
            acc[4 * q + 3] = fmaf(kv, v.w, acc[4 * q + 3]);
        }
    }

    // ---- store out (output 1, f32) ----
    float4* op = (float4*)(out + (size_t)p * CC);
#pragma unroll
    for (int q = 0; q < 16; ++q)
        op[q] = make_float4(acc[4 * q + 0], acc[4 * q + 1], acc[4 * q + 2], acc[4 * q + 3]);
}

extern "C" void kernel_launch(void* const* d_in, const int* in_sizes, int n_in,
                              void* d_out, int out_size, void* d_ws, size_t ws_size,
                              hipStream_t stream) {
    const float* x       = (const float*)d_in[0];
    const float* w1      = (const float*)d_in[1];
    const float* b1      = (const float*)d_in[2];
    const float* gamma   = (const float*)d_in[3];
    const float* beta    = (const float*)d_in[4];
    const float* bn_mean = (const float*)d_in[5];
    const float* bn_var  = (const float*)d_in[6];
    const float* w2      = (const float*)d_in[7];
    const float* b2      = (const float*)d_in[8];

    float* w1t    = (float*)d_ws;          // 4096
    float* w2f    = w1t + CC * CC;         // 576
    float* scalef = w2f + CC * KK;         // 64
    float* biasf  = scalef + CC;           // 64
    float* b2f    = biasf + CC;            // 9

    float* out  = (float*)d_out;
    float* kout = out + (size_t)NPIX * CC;

    hipLaunchKernelGGL(setup_kernel, dim3(20), dim3(256), 0, stream,
                       w1, b1, gamma, beta, bn_mean, bn_var, w2, b2,
                       w1t, w2f, scalef, biasf, b2f);

    hipLaunchKernelGGL(invol_kernel, dim3(NPIX / 256), dim3(256), 0, stream,
                       x, w1t, w2f, scalef, biasf, b2f, out, kout);
}

// Round 4
// 76.173 us; speedup vs baseline: 1.2003x; 1.2003x over previous
//
#include <hip/hip_runtime.h>

typedef unsigned int uint;

#define BATCH 8
#define HH 128
#define WW 128
#define CC 64
#define NPIX (BATCH * HH * WW)   // 131072
#define KK 9
#define BN_EPS 1e-3f
#define PIXB 64                   // pixels per block

// ---- setup: transpose w1, fold b1 + BN into per-channel scale/bias ----
__global__ void setup_kernel(const float* __restrict__ w1,
                             const float* __restrict__ b1,
                             const float* __restrict__ gamma,
                             const float* __restrict__ beta,
                             const float* __restrict__ bn_mean,
                             const float* __restrict__ bn_var,
                             const float* __restrict__ w2,
                             const float* __restrict__ b2,
                             float* __restrict__ w1t,    // [64][64]: w1t[d][c] = w1[c][d]
                             float* __restrict__ w2f,    // [64][9]
                             float* __restrict__ scalef, // [64]
                             float* __restrict__ biasf,  // [64]
                             float* __restrict__ b2f)    // [9]
{
    int t = blockIdx.x * blockDim.x + threadIdx.x;
    int nt = gridDim.x * blockDim.x;
    for (int idx = t; idx < CC * CC; idx += nt) {
        int d = idx >> 6, c = idx & 63;
        w1t[idx] = w1[c * CC + d];
    }
    for (int idx = t; idx < CC * KK; idx += nt) w2f[idx] = w2[idx];
    if (t < CC) {
        float s = gamma[t] * rsqrtf(bn_var[t] + BN_EPS);
        scalef[t] = s;
        biasf[t] = (b1[t] - bn_mean[t]) * s + beta[t];
    }
    if (t < KK) b2f[t] = b2[t];
}

// ---- fused kernel: block = 64 pixels, wave = d-quarter / channel-quarter ----
__global__ __launch_bounds__(256) void invol_kernel(
    const float* __restrict__ x,
    const float* __restrict__ w1t,
    const float* __restrict__ w2f,
    const float* __restrict__ scalef,
    const float* __restrict__ biasf,
    const float* __restrict__ b2f,
    float* __restrict__ out,     // [NPIX][64]
    float* __restrict__ kout)    // [NPIX][9]
{
    __shared__ float xT[CC][PIXB];     // xT[c][p] — transposed tile, 16 KB
    __shared__ float part[PIXB][37];   // [pixel][q*9+k] partials; stride 37 → ~2-way banks

    const int t = threadIdx.x;
    const int p0 = blockIdx.x * PIXB;
    const int lane = t & 63;
    const int q = t >> 6;
    const int qu = __builtin_amdgcn_readfirstlane(q);   // force SGPR → s_load weights

    // ---- stage x tile transposed: thread (lane=pixel, wave=16-ch chunk) ----
    {
        const float4* g = (const float4*)(x + (size_t)(p0 + lane) * CC + qu * 16);
#pragma unroll
        for (int f = 0; f < 4; ++f) {
            float4 v = g[f];
            int c = qu * 16 + f * 4;
            xT[c + 0][lane] = v.x; xT[c + 1][lane] = v.y;
            xT[c + 2][lane] = v.z; xT[c + 3][lane] = v.w;
        }
    }
    __syncthreads();

    // ---- GEMM: wave q computes h[d] for d in [16q, 16q+16) of its lane's pixel ----
    const float* w1q = w1t + qu * 16 * CC;      // SGPR base → uniform s_loads
    const float* sq  = scalef + qu * 16;
    const float* bq  = biasf + qu * 16;
    const float* w2q = w2f + qu * 16 * KK;

    float h[16];
#pragma unroll
    for (int dd = 0; dd < 16; ++dd) h[dd] = 0.f;

#pragma unroll 2
    for (int c4 = 0; c4 < 16; ++c4) {
        float xv[4];
#pragma unroll
        for (int e = 0; e < 4; ++e) xv[e] = xT[c4 * 4 + e][lane];
#pragma unroll
        for (int dd = 0; dd < 16; ++dd) {
#pragma unroll
            for (int e = 0; e < 4; ++e)
                h[dd] = fmaf(xv[e], w1q[dd * CC + c4 * 4 + e], h[dd]);
        }
    }

    // ---- BN + ReLU + kern partials ----
    float kp[KK];
#pragma unroll
    for (int k = 0; k < KK; ++k) kp[k] = 0.f;
#pragma unroll
    for (int dd = 0; dd < 16; ++dd) {
        float hv = fmaxf(fmaf(h[dd], sq[dd], bq[dd]), 0.f);
#pragma unroll
        for (int k = 0; k < KK; ++k)
            kp[k] = fmaf(hv, w2q[dd * KK + k], kp[k]);
    }
#pragma unroll
    for (int k = 0; k < KK; ++k) part[lane][q * KK + k] = kp[k];
    __syncthreads();

    // ---- reduce kern over 4 waves; add b2; write kout; stash in part[p][k] ----
#pragma unroll
    for (int m = 0; m < 3; ++m) {
        int pid = t + m * 256;
        if (pid < PIXB * KK) {
            int pp = pid / KK, kk = pid - pp * KK;
            float s = part[pp][0 * KK + kk] + part[pp][1 * KK + kk]
                    + part[pp][2 * KK + kk] + part[pp][3 * KK + kk] + b2f[kk];
            part[pp][kk] = s;                       // only this thread touches [pp][kk]
            kout[(size_t)(p0 + pp) * KK + kk] = s;
        }
    }
    __syncthreads();

    // ---- involution: wave q handles channels [16q,16q+16) of lane's pixel ----
    const int pix = p0 + lane;
    const int b = pix >> 14;
    const int i = (pix >> 7) & 127;
    const int j = pix & 127;
    const int c0 = qu * 16;

    float kern[KK];
#pragma unroll
    for (int k = 0; k < KK; ++k) kern[k] = part[lane][k];

    float acc[16];
#pragma unroll
    for (int e = 0; e < 16; ++e) acc[e] = kern[4] * xT[c0 + e][lane];

#pragma unroll
    for (int tap = 0; tap < KK; ++tap) {
        if (tap == 4) continue;
        const int di = tap / 3 - 1, dj = tap % 3 - 1;
        int ii = i + di, jj = j + dj;
        bool valid = (ii >= 0) && (ii < HH) && (jj >= 0) && (jj < WW);
        float kv = valid ? kern[tap] : 0.f;
        int iic = min(max(ii, 0), HH - 1);
        int jjc = min(max(jj, 0), WW - 1);
        const float4* np = (const float4*)(x + (((size_t)b * HH + iic) * WW + jjc) * CC + c0);
#pragma unroll
        for (int f = 0; f < 4; ++f) {
            float4 v = np[f];
            acc[f * 4 + 0] = fmaf(kv, v.x, acc[f * 4 + 0]);
            acc[f * 4 + 1] = fmaf(kv, v.y, acc[f * 4 + 1]);
            acc[f * 4 + 2] = fmaf(kv, v.z, acc[f * 4 + 2]);
            acc[f * 4 + 3] = fmaf(kv, v.w, acc[f * 4 + 3]);
        }
    }

    float4* op = (float4*)(out + (size_t)pix * CC + c0);
#pragma unroll
    for (int f = 0; f < 4; ++f)
        op[f] = make_float4(acc[f * 4 + 0], acc[f * 4 + 1], acc[f * 4 + 2], acc[f * 4 + 3]);
}

extern "C" void kernel_launch(void* const* d_in, const int* in_sizes, int n_in,
                              void* d_out, int out_size, void* d_ws, size_t ws_size,
                              hipStream_t stream) {
    const float* x       = (const float*)d_in[0];
    const float* w1      = (const float*)d_in[1];
    const float* b1      = (const float*)d_in[2];
    const float* gamma   = (const float*)d_in[3];
    const float* beta    = (const float*)d_in[4];
    const float* bn_mean = (const float*)d_in[5];
    const float* bn_var  = (const float*)d_in[6];
    const float* w2      = (const float*)d_in[7];
    const float* b2      = (const float*)d_in[8];

    float* w1t    = (float*)d_ws;          // 4096
    float* w2f    = w1t + CC * CC;         // 576
    float* scalef = w2f + CC * KK;         // 64
    float* biasf  = scalef + CC;           // 64
    float* b2f    = biasf + CC;            // 9

    float* out  = (float*)d_out;
    float* kout = out + (size_t)NPIX * CC;

    hipLaunchKernelGGL(setup_kernel, dim3(20), dim3(256), 0, stream,
                       w1, b1, gamma, beta, bn_mean, bn_var, w2, b2,
                       w1t, w2f, scalef, biasf, b2f);

    hipLaunchKernelGGL(invol_kernel, dim3(NPIX / PIXB), dim3(256), 0, stream,
                       x, w1t, w2f, scalef, biasf, b2f, out, kout);
}